// Round 2
// baseline (515.773 us; speedup 1.0000x reference)
//
#include <hip/hip_runtime.h>
#include <hip/hip_fp16.h>

#define BB 4
#define SS 2048
#define HH 16
#define DKK 64
#define DMODEL 1024

typedef __attribute__((ext_vector_type(8))) _Float16 half8;
typedef __attribute__((ext_vector_type(4))) _Float16 half4;
typedef __attribute__((ext_vector_type(2))) __fp16 fp16x2;
typedef __attribute__((ext_vector_type(4))) float floatx4;

#define MFMA16(a, b, c) __builtin_amdgcn_mfma_f32_16x16x32_f16(a, b, c, 0, 0, 0)

// 8 * log2(e): reference scale is *8; softmax runs in exp2 domain.
// Folded into the Q projection epilogue (Qh is pre-scaled).
#define SCL2 11.5415603336f

// ---------------- async global->LDS, 16B per lane ------------------------------
__device__ __forceinline__ void gload_lds16(const _Float16* g, _Float16* l) {
    __builtin_amdgcn_global_load_lds(
        (const __attribute__((address_space(1))) void*)g,
        (__attribute__((address_space(3))) void*)l, 16, 0, 0);
}

// ---------------- fp32 -> fp16 convert of X body, k-unit XOR swizzle -----------
__device__ __forceinline__
void convert_x_body(const float* __restrict__ src, _Float16* __restrict__ dst,
                    int bidx)
{
    size_t base = ((size_t)bidx * 256 + threadIdx.x) * 8;
    int m = (int)(base >> 10);
    int kk = (int)(base & 1023);
    float4 a = *(const float4*)(src + base);
    float4 b = *(const float4*)(src + base + 4);
    half8 h;
    h[0] = (_Float16)a.x; h[1] = (_Float16)a.y; h[2] = (_Float16)a.z; h[3] = (_Float16)a.w;
    h[4] = (_Float16)b.x; h[5] = (_Float16)b.y; h[6] = (_Float16)b.z; h[7] = (_Float16)b.w;
    int kd = kk ^ ((m & 7) << 3);
    *(half8*)(dst + ((size_t)m << 10) + kd) = h;
}

// ---------------- W[k][n] -> WT[n][k] fp16 body, swizzle by (n&7) --------------
__device__ __forceinline__
void convert_wt_body(const float* __restrict__ W, _Float16* __restrict__ WT,
                     int bidx)
{
    __shared__ __attribute__((aligned(16))) _Float16 T[64][72];
    int kt = (bidx >> 4) << 6;
    int nt = (bidx & 15) << 6;
    int tid = threadIdx.x;
    #pragma unroll
    for (int p = 0; p < 4; p++) {
        int lin = tid + p * 256;
        int row = lin >> 4;
        int c4 = (lin & 15) << 2;
        float4 vv = *(const float4*)(W + (size_t)(kt + row) * DMODEL + nt + c4);
        T[c4 + 0][row] = (_Float16)vv.x;
        T[c4 + 1][row] = (_Float16)vv.y;
        T[c4 + 2][row] = (_Float16)vv.z;
        T[c4 + 3][row] = (_Float16)vv.w;
    }
    __syncthreads();
    #pragma unroll
    for (int p = 0; p < 2; p++) {
        int lin = tid + p * 256;
        int nl = lin >> 3;
        int u = lin & 7;
        half8 h = *(const half8*)&T[nl][u * 8];
        int n = nt + nl;
        int kd = kt + ((u ^ (n & 7)) << 3);
        *(half8*)(WT + (size_t)n * DMODEL + kd) = h;
    }
}

__global__ __launch_bounds__(256)
void convert_x(const float* __restrict__ q, const float* __restrict__ k,
               const float* __restrict__ v, _Float16* __restrict__ xq,
               _Float16* __restrict__ xk, _Float16* __restrict__ xv)
{
    int z = blockIdx.y;
    convert_x_body(z == 0 ? q : z == 1 ? k : v,
                   z == 0 ? xq : z == 1 ? xk : xv, blockIdx.x);
}

__global__ __launch_bounds__(256)
void convert_wt(const float* __restrict__ wq, const float* __restrict__ wk,
                const float* __restrict__ wv, _Float16* __restrict__ tq,
                _Float16* __restrict__ tk, _Float16* __restrict__ tv)
{
    int z = blockIdx.y;
    convert_wt_body(z == 0 ? wq : z == 1 ? wk : wv,
                    z == 0 ? tq : z == 1 ? tk : tv, blockIdx.x);
}

// fused converts: y=0..2 -> X converts; y=3 -> the 768 WT blocks
__global__ __launch_bounds__(256)
void convert_all(const float* __restrict__ q, const float* __restrict__ k,
                 const float* __restrict__ v, const float* __restrict__ wq,
                 const float* __restrict__ wk, const float* __restrict__ wv,
                 _Float16* __restrict__ xq, _Float16* __restrict__ xk,
                 _Float16* __restrict__ xv, _Float16* __restrict__ tq,
                 _Float16* __restrict__ tk, _Float16* __restrict__ tv)
{
    int y = blockIdx.y;
    if (y < 3) {
        convert_x_body(y == 0 ? q : y == 1 ? k : v,
                       y == 0 ? xq : y == 1 ? xk : xv, blockIdx.x);
    } else {
        if (blockIdx.x >= 768) return;
        int z = blockIdx.x >> 8;
        convert_wt_body(z == 0 ? wq : z == 1 ? wk : wv,
                        z == 0 ? tq : z == 1 ? tk : tv, blockIdx.x & 255);
    }
}

// ---------------- 128x128 projection GEMM body ---------------------------------
// XCD-aware tile map: the 8 n-blocks sharing one X m-tile all get the same
// bidx%8 -> same XCD. scl: epilogue scale ((acc+bias)*scl) -- SCL2 for Q.
// SWZ=1 pre-swizzles the stored layout for flash3's LDS staging (rule #21:
// global_load_lds dest must stay linear, so the swizzle lives in the data):
//   VMODE=0 (K): d-block index ^= (s&7)   -> Ks ds_read conflict spread
//   VMODE=1 (V): s-block index ^= (d&7)   -> Vs ds_read conflict spread
template <int VMODE, int SWZ>
__device__ __forceinline__
void proj_body(const _Float16* __restrict__ X, const _Float16* __restrict__ WT,
               const float* __restrict__ bias, _Float16* __restrict__ out,
               int bidx, float scl)
{
    __shared__ __attribute__((aligned(16))) _Float16 As[128 * 64];
    __shared__ __attribute__((aligned(16))) _Float16 Bs[128 * 64];
    const int tid = threadIdx.x;
    const int wave = tid >> 6, lane = tid & 63, quad = lane >> 4, l16 = lane & 15;
    const int wm = wave >> 1, wn = wave & 1;
    const int m0 = ((bidx & 7) | ((bidx >> 6) << 3)) << 7;
    const int n0 = ((bidx >> 3) & 7) << 7;
    const int lrow = lane >> 3;
    const int lcol = (lane & 7) << 3;

    floatx4 acc[4][4] = {};

    for (int k0 = 0; k0 < DMODEL; k0 += 64) {
        __syncthreads();
        #pragma unroll
        for (int c = 0; c < 4; c++) {
            int row = c * 32 + wave * 8;
            gload_lds16(X + (size_t)(m0 + row + lrow) * DMODEL + k0 + lcol,
                        As + (size_t)row * 64);
            gload_lds16(WT + (size_t)(n0 + row + lrow) * DMODEL + k0 + lcol,
                        Bs + (size_t)row * 64);
        }
        __syncthreads();
        #pragma unroll
        for (int ks = 0; ks < 2; ks++) {
            int ccol = ((ks * 4 + quad) ^ (l16 & 7)) << 3;
            half8 af[4], bf[4];
            #pragma unroll
            for (int i = 0; i < 4; i++)
                af[i] = *(const half8*)(As + (wm * 64 + i * 16 + l16) * 64 + ccol);
            #pragma unroll
            for (int j = 0; j < 4; j++)
                bf[j] = *(const half8*)(Bs + (wn * 64 + j * 16 + l16) * 64 + ccol);
            #pragma unroll
            for (int i = 0; i < 4; i++)
                #pragma unroll
                for (int j = 0; j < 4; j++)
                    acc[i][j] = VMODE ? MFMA16(bf[j], af[i], acc[i][j])
                                      : MFMA16(af[i], bf[j], acc[i][j]);
        }
    }

    if (VMODE == 0) {
        #pragma unroll
        for (int j = 0; j < 4; j++) {
            int ng = n0 + wn * 64 + j * 16 + l16;
            int h = ng >> 6, d = ng & 63;
            float bv = bias[ng];
            #pragma unroll
            for (int i = 0; i < 4; i++)
                #pragma unroll
                for (int r = 0; r < 4; r++) {
                    int mg = m0 + wm * 64 + i * 16 + quad * 4 + r;
                    int bb = mg >> 11, s = mg & 2047;
                    int dd = SWZ ? ((((d >> 3) ^ (s & 7)) << 3) | (d & 7)) : d;
                    out[(((size_t)bb * HH + h) * SS + s) * DKK + dd] =
                        (_Float16)((acc[i][j][r] + bv) * scl);
                }
        }
    } else {
        #pragma unroll
        for (int j = 0; j < 4; j++)
            #pragma unroll
            for (int r = 0; r < 4; r++) {
                int ng = n0 + wn * 64 + j * 16 + quad * 4 + r;
                int h = ng >> 6, d = ng & 63;
                float bv = bias[ng];
                #pragma unroll
                for (int i = 0; i < 4; i++) {
                    int mg = m0 + wm * 64 + i * 16 + l16;
                    int bb = mg >> 11, s = mg & 2047;
                    int ss2 = SWZ ? (s ^ ((d & 7) << 3)) : s;
                    out[(((size_t)bb * HH + h) * DKK + d) * SS + ss2] =
                        (_Float16)((acc[i][j][r] + bv) * scl);
                }
            }
    }
}

template <int VMODE, int SWZ>
__global__ __launch_bounds__(256)
void proj128(const _Float16* __restrict__ X, const _Float16* __restrict__ WT,
             const float* __restrict__ bias, _Float16* __restrict__ out, float scl)
{
    proj_body<VMODE, SWZ>(X, WT, bias, out, blockIdx.x, scl);
}

// all three projections in one launch (requires non-aliased buffers)
__global__ __launch_bounds__(256)
void proj_all(const _Float16* __restrict__ Xq, const _Float16* __restrict__ Xk,
              const _Float16* __restrict__ Xv, const _Float16* __restrict__ WTq,
              const _Float16* __restrict__ WTk, const _Float16* __restrict__ WTv,
              const float* __restrict__ bq, const float* __restrict__ bk,
              const float* __restrict__ bv, _Float16* __restrict__ Qh,
              _Float16* __restrict__ Kh, _Float16* __restrict__ VTh)
{
    int z = blockIdx.y;
    if (z == 0)      proj_body<0, 0>(Xq, WTq, bq, Qh, blockIdx.x, SCL2);
    else if (z == 1) proj_body<0, 1>(Xk, WTk, bk, Kh, blockIdx.x, 1.0f);
    else             proj_body<1, 1>(Xv, WTv, bv, VTh, blockIdx.x, 1.0f);
}

// ---------------- flash attention v5: LDS-staged K/V, 2-phase async pipeline ---
// Per kt: all 4 waves cooperatively DMA the 8KB K-tile + 8KB V-tile into LDS
// (double-buffered), counted vmcnt(4) + raw s_barrier keeps next-tile loads in
// flight across the barrier (T3/T4). K/V global layouts are pre-swizzled by the
// projection so linear DMA + XOR'd ds_read_b128 is conflict-spread.
__global__ __launch_bounds__(256)
void flash3(const _Float16* __restrict__ Qw, const _Float16* __restrict__ Kw,
            const _Float16* __restrict__ VTw, const int* __restrict__ mask,
            const float* __restrict__ resid, float* __restrict__ out)
{
    __shared__ float Bias[SS];                                            // 8 KB
    __shared__ __attribute__((aligned(16))) _Float16 Plds[4][2][16][64];  // 16 KB
    __shared__ __attribute__((aligned(16))) _Float16 Ks[2][4096];         // 16 KB
    __shared__ __attribute__((aligned(16))) _Float16 Vs[2][4096];         // 16 KB

    const int tid = threadIdx.x;
    const int wave = tid >> 6, lane = tid & 63, quad = lane >> 4, l16 = lane & 15;
    const int bx = blockIdx.x;
    const int xcd = bx & 7;
    const int jj = bx >> 3;
    const int bh = ((jj >> 4) << 3) | xcd;   // all 16 q-tiles of a bh on one XCD
    const int qt = jj & 15;
    const int b = bh >> 4;
    const int h = bh & 15;
    const int qbase = qt * 128 + wave * 32;
    const int sw = l16 & 7;

    const _Float16* Kbase = Kw + (size_t)bh * SS * DKK;
    const _Float16* Vbase = VTw + (size_t)bh * DKK * SS;

    // Q B-frags first (vmcnt bookkeeping: these drain under the first vmcnt(4))
    half8 qf[2][2];
    #pragma unroll
    for (int mt = 0; mt < 2; mt++) {
        const _Float16* Qp = Qw + ((size_t)bh * SS + qbase + mt * 16 + l16) * DKK;
        qf[mt][0] = *(const half8*)(Qp + quad * 8);
        qf[mt][1] = *(const half8*)(Qp + 32 + quad * 8);
    }

    // prologue: stage kt=0 (4 async DMA loads per thread)
    #pragma unroll
    for (int c = 0; c < 2; c++) {
        int chunk = wave * 2 + c;
        gload_lds16(Kbase + chunk * 512 + lane * 8, &Ks[0][chunk * 512]);
        gload_lds16(Vbase + (size_t)(chunk * 8 + (lane >> 3)) * SS + (lane & 7) * 8,
                    &Vs[0][chunk * 512]);
    }

    // stage mask -> fp32 additive bias (exp2 domain; -1e9 kills)
    const int* mk = mask + b * SS;
    for (int i = tid; i < SS; i += 256)
        Bias[i] = mk[i] ? 0.f : -1.0e9f;
    // Bias visibility barrier WITHOUT draining vmcnt (keep DMA in flight)
    asm volatile("s_waitcnt lgkmcnt(0)" ::: "memory");
    __builtin_amdgcn_s_barrier();

    float mrow[2] = {-3.0e38f, -3.0e38f};
    float lrow[2] = {0.f, 0.f};
    floatx4 oacc[2][4] = {};   // O^T: [mt][dt]; col=l16=q, row=quad*4+r=d-local

    for (int kt = 0; kt < SS / 64; kt++) {
        const int cur = kt & 1;
        const _Float16* Kl = Ks[cur];
        const _Float16* Vl = Vs[cur];
        const int kb = kt << 6;

        if (kt < SS / 64 - 1) {
            const int kb1 = kb + 64;
            #pragma unroll
            for (int c = 0; c < 2; c++) {
                int chunk = wave * 2 + c;
                gload_lds16(Kbase + (size_t)kb1 * DKK + chunk * 512 + lane * 8,
                            &Ks[cur ^ 1][chunk * 512]);
                gload_lds16(Vbase + (size_t)(chunk * 8 + (lane >> 3)) * SS + kb1
                                + (lane & 7) * 8,
                            &Vs[cur ^ 1][chunk * 512]);
            }
            asm volatile("s_waitcnt vmcnt(4)" ::: "memory");  // cur tile landed
        } else {
            asm volatile("s_waitcnt vmcnt(0)" ::: "memory");
        }
        __builtin_amdgcn_s_barrier();   // B1: cur tile visible to all waves

        // acc init = mask bias (keys kb + k2*16 + quad*4 + r; same for both mt)
        floatx4 sacc[2][4];
        #pragma unroll
        for (int k2 = 0; k2 < 4; k2++) {
            float4 bv = *(const float4*)&Bias[kb + k2 * 16 + quad * 4];
            floatx4 bi = {bv.x, bv.y, bv.z, bv.w};
            sacc[0][k2] = bi;
            sacc[1][k2] = bi;
        }

        // K A-frags from LDS: row=k2*16+l16, block=(ks*4+quad)^(row&7)
        half8 kf[2][4];
        #pragma unroll
        for (int ks = 0; ks < 2; ks++)
            #pragma unroll
            for (int k2 = 0; k2 < 4; k2++)
                kf[ks][k2] = *(const half8*)(Kl + (k2 * 16 + l16) * 64
                                + (((ks * 4 + quad) ^ sw) << 3));

        // S^T: D[m=key][n=q] = SCL2*QK + bias
        #pragma unroll
        for (int mt = 0; mt < 2; mt++)
            #pragma unroll
            for (int ks = 0; ks < 2; ks++)
                #pragma unroll
                for (int k2 = 0; k2 < 4; k2++)
                    sacc[mt][k2] = MFMA16(kf[ks][k2], qf[mt][ks], sacc[mt][k2]);

        // V^T A-frags from LDS: row=dt*16+l16, block=(ks*4+quad)^(row&7)
        half8 vf[2][4];
        #pragma unroll
        for (int ks = 0; ks < 2; ks++)
            #pragma unroll
            for (int dt = 0; dt < 4; dt++)
                vf[ks][dt] = *(const half8*)(Vl + (dt * 16 + l16) * 64
                                + (((ks * 4 + quad) ^ sw) << 3));

        #pragma unroll
        for (int mt = 0; mt < 2; mt++) {
            floatx4* S = sacc[mt];

            // row max: depth-4 tree + cross-quad (lanes ^16, ^32)
            float t4[4];
            #pragma unroll
            for (int k2 = 0; k2 < 4; k2++)
                t4[k2] = fmaxf(fmaxf(S[k2][0], S[k2][1]),
                               fmaxf(S[k2][2], S[k2][3]));
            float t = fmaxf(fmaxf(t4[0], t4[1]), fmaxf(t4[2], t4[3]));
            t = fmaxf(t, __shfl_xor(t, 16, 64));
            t = fmaxf(t, __shfl_xor(t, 32, 64));

            float mn = fmaxf(mrow[mt], t);
            float al = exp2f(mrow[mt] - mn);
            mrow[mt] = mn;

            // exp2 in place, write P to LDS ASAP, partial-sum tree
            float ss[4];
            #pragma unroll
            for (int k2 = 0; k2 < 4; k2++) {
                #pragma unroll
                for (int r = 0; r < 4; r++)
                    S[k2][r] = exp2f(S[k2][r] - mn);
                union { fp16x2 h2[2]; half4 h4; } u;
                u.h2[0] = __builtin_amdgcn_cvt_pkrtz(S[k2][0], S[k2][1]);
                u.h2[1] = __builtin_amdgcn_cvt_pkrtz(S[k2][2], S[k2][3]);
                int cbw = ((((k2 << 1) | (quad >> 1)) ^ sw) << 3) | ((quad & 1) << 2);
                *(half4*)&Plds[wave][mt][l16][cbw] = u.h4;
                ss[k2] = (S[k2][0] + S[k2][1]) + (S[k2][2] + S[k2][3]);
            }
            float ps = (ss[0] + ss[1]) + (ss[2] + ss[3]);
            ps += __shfl_xor(ps, 16, 64);
            ps += __shfl_xor(ps, 32, 64);
            lrow[mt] = lrow[mt] * al + ps;

            // alpha rescale
            #pragma unroll
            for (int dt = 0; dt < 4; dt++)
                oacc[mt][dt] *= al;

            // PV: O^T += V^T x P^T  (A=vf m=d, B=pf n=q); swizzled b128 reads
            #pragma unroll
            for (int ks = 0; ks < 2; ks++) {
                half8 pf = *(const half8*)
                    &Plds[wave][mt][l16][((ks * 4 + quad) ^ sw) << 3];
                #pragma unroll
                for (int dt = 0; dt < 4; dt++)
                    oacc[mt][dt] = MFMA16(vf[ks][dt], pf, oacc[mt][dt]);
            }
        }
        __builtin_amdgcn_s_barrier();   // B2: all done with cur before re-stage
    }

    // epilogue: float4 loads/stores
    #pragma unroll
    for (int mt = 0; mt < 2; mt++) {
        float rl = 1.0f / lrow[mt];
        int s = qbase + mt * 16 + l16;
        size_t rowoff = ((size_t)b * SS + s) * DMODEL + h * DKK;
        #pragma unroll
        for (int dt = 0; dt < 4; dt++) {
            size_t gi = rowoff + dt * 16 + quad * 4;
            float4 rv = *(const float4*)&resid[gi];
            float4 ov;
            ov.x = oacc[mt][dt][0] * rl + rv.x;
            ov.y = oacc[mt][dt][1] * rl + rv.y;
            ov.z = oacc[mt][dt][2] * rl + rv.z;
            ov.w = oacc[mt][dt][3] * rl + rv.w;
            *(float4*)&out[gi] = ov;
        }
    }
}

// ---------------------------------------------------------------------------
extern "C" void kernel_launch(void* const* d_in, const int* in_sizes, int n_in,
                              void* d_out, int out_size, void* d_ws, size_t ws_size,
                              hipStream_t stream)
{
    const float* q    = (const float*)d_in[0];
    const float* k    = (const float*)d_in[1];
    const float* v    = (const float*)d_in[2];
    const int*   mask = (const int*)d_in[3];
    const float* wq   = (const float*)d_in[4];
    const float* bq   = (const float*)d_in[5];
    const float* wk   = (const float*)d_in[6];
    const float* bk   = (const float*)d_in[7];
    const float* wv   = (const float*)d_in[8];
    const float* bv   = (const float*)d_in[9];
    float* out = (float*)d_out;

    const size_t TENS = (size_t)BB * SS * HH * DKK;   // 8388608 halves
    const size_t WSZ  = (size_t)DMODEL * DMODEL;      // 1048576 halves
    _Float16* base = (_Float16*)d_ws;

    bool big = ws_size >= (6 * TENS + 3 * WSZ) * sizeof(_Float16);
    _Float16 *Xq, *Xk, *Xv, *Qh, *Kh, *VTh, *WTq;
    if (big) {
        Xq = base;            Xk = base + TENS;     Xv = base + 2 * TENS;
        Qh = base + 3 * TENS; Kh = base + 4 * TENS; VTh = base + 5 * TENS;
        WTq = base + 6 * TENS;
    } else {
        // stream-ordered aliasing: Kh reuses Xq's slot, VTh reuses Xk's slot
        Xq = base;            Xk = base + TENS;     Xv = base + 2 * TENS;
        Qh = base + 3 * TENS; Kh = Xq;              VTh = Xk;
        WTq = base + 4 * TENS;
    }
    _Float16* WTk = WTq + WSZ;
    _Float16* WTv = WTk + WSZ;

    if (big) {
        hipLaunchKernelGGL(convert_all, dim3(4096, 4), dim3(256), 0, stream,
                           q, k, v, wq, wk, wv, Xq, Xk, Xv, WTq, WTk, WTv);
        hipLaunchKernelGGL(proj_all, dim3(512, 3), dim3(256), 0, stream,
                           Xq, Xk, Xv, WTq, WTk, WTv, bq, bk, bv, Qh, Kh, VTh);
    } else {
        hipLaunchKernelGGL(convert_x, dim3(4096, 3), dim3(256), 0, stream,
                           q, k, v, Xq, Xk, Xv);
        hipLaunchKernelGGL(convert_wt, dim3(256, 3), dim3(256), 0, stream,
                           wq, wk, wv, WTq, WTk, WTv);
        hipLaunchKernelGGL((proj128<0, 0>), dim3(512), dim3(256), 0, stream, Xq, WTq, bq, Qh, SCL2);
        hipLaunchKernelGGL((proj128<0, 1>), dim3(512), dim3(256), 0, stream, Xk, WTk, bk, Kh, 1.0f);
        hipLaunchKernelGGL((proj128<1, 1>), dim3(512), dim3(256), 0, stream, Xv, WTv, bv, VTh, 1.0f);
    }
    hipLaunchKernelGGL(flash3, dim3(BB * HH * (SS / 128)), dim3(256), 0, stream,
                       Qh, Kh, VTh, mask, q, out);
}

// Round 3
// 469.197 us; speedup vs baseline: 1.0993x; 1.0993x over previous
//
#include <hip/hip_runtime.h>
#include <hip/hip_fp16.h>

#define BB 4
#define SS 2048
#define HH 16
#define DKK 64
#define DMODEL 1024

typedef __attribute__((ext_vector_type(8))) _Float16 half8;
typedef __attribute__((ext_vector_type(4))) _Float16 half4;
typedef __attribute__((ext_vector_type(2))) __fp16 fp16x2;
typedef __attribute__((ext_vector_type(4))) float floatx4;

#define MFMA16(a, b, c) __builtin_amdgcn_mfma_f32_16x16x32_f16(a, b, c, 0, 0, 0)

// 8 * log2(e): reference scale is *8; softmax runs in exp2 domain.
// Folded into the Q projection epilogue (Qh is pre-scaled).
#define SCL2 11.5415603336f

// ---------------- async global->LDS, 16B per lane ------------------------------
__device__ __forceinline__ void gload_lds16(const _Float16* g, _Float16* l) {
    __builtin_amdgcn_global_load_lds(
        (const __attribute__((address_space(1))) void*)g,
        (__attribute__((address_space(3))) void*)l, 16, 0, 0);
}

// ---------------- fp32 -> fp16 convert of X body, k-unit XOR swizzle -----------
__device__ __forceinline__
void convert_x_body(const float* __restrict__ src, _Float16* __restrict__ dst,
                    int bidx)
{
    size_t base = ((size_t)bidx * 256 + threadIdx.x) * 8;
    int m = (int)(base >> 10);
    int kk = (int)(base & 1023);
    float4 a = *(const float4*)(src + base);
    float4 b = *(const float4*)(src + base + 4);
    half8 h;
    h[0] = (_Float16)a.x; h[1] = (_Float16)a.y; h[2] = (_Float16)a.z; h[3] = (_Float16)a.w;
    h[4] = (_Float16)b.x; h[5] = (_Float16)b.y; h[6] = (_Float16)b.z; h[7] = (_Float16)b.w;
    int kd = kk ^ ((m & 7) << 3);
    *(half8*)(dst + ((size_t)m << 10) + kd) = h;
}

// ---------------- W[k][n] -> WT[n][k] fp16 body, swizzle by (n&7) --------------
__device__ __forceinline__
void convert_wt_body(const float* __restrict__ W, _Float16* __restrict__ WT,
                     int bidx)
{
    __shared__ __attribute__((aligned(16))) _Float16 T[64][72];
    int kt = (bidx >> 4) << 6;
    int nt = (bidx & 15) << 6;
    int tid = threadIdx.x;
    #pragma unroll
    for (int p = 0; p < 4; p++) {
        int lin = tid + p * 256;
        int row = lin >> 4;
        int c4 = (lin & 15) << 2;
        float4 vv = *(const float4*)(W + (size_t)(kt + row) * DMODEL + nt + c4);
        T[c4 + 0][row] = (_Float16)vv.x;
        T[c4 + 1][row] = (_Float16)vv.y;
        T[c4 + 2][row] = (_Float16)vv.z;
        T[c4 + 3][row] = (_Float16)vv.w;
    }
    __syncthreads();
    #pragma unroll
    for (int p = 0; p < 2; p++) {
        int lin = tid + p * 256;
        int nl = lin >> 3;
        int u = lin & 7;
        half8 h = *(const half8*)&T[nl][u * 8];
        int n = nt + nl;
        int kd = kt + ((u ^ (n & 7)) << 3);
        *(half8*)(WT + (size_t)n * DMODEL + kd) = h;
    }
}

__global__ __launch_bounds__(256)
void convert_x(const float* __restrict__ q, const float* __restrict__ k,
               const float* __restrict__ v, _Float16* __restrict__ xq,
               _Float16* __restrict__ xk, _Float16* __restrict__ xv)
{
    int z = blockIdx.y;
    convert_x_body(z == 0 ? q : z == 1 ? k : v,
                   z == 0 ? xq : z == 1 ? xk : xv, blockIdx.x);
}

__global__ __launch_bounds__(256)
void convert_wt(const float* __restrict__ wq, const float* __restrict__ wk,
                const float* __restrict__ wv, _Float16* __restrict__ tq,
                _Float16* __restrict__ tk, _Float16* __restrict__ tv)
{
    int z = blockIdx.y;
    convert_wt_body(z == 0 ? wq : z == 1 ? wk : wv,
                    z == 0 ? tq : z == 1 ? tk : tv, blockIdx.x);
}

// fused converts: y=0..2 -> X converts; y=3 -> the 768 WT blocks
__global__ __launch_bounds__(256)
void convert_all(const float* __restrict__ q, const float* __restrict__ k,
                 const float* __restrict__ v, const float* __restrict__ wq,
                 const float* __restrict__ wk, const float* __restrict__ wv,
                 _Float16* __restrict__ xq, _Float16* __restrict__ xk,
                 _Float16* __restrict__ xv, _Float16* __restrict__ tq,
                 _Float16* __restrict__ tk, _Float16* __restrict__ tv)
{
    int y = blockIdx.y;
    if (y < 3) {
        convert_x_body(y == 0 ? q : y == 1 ? k : v,
                       y == 0 ? xq : y == 1 ? xk : xv, blockIdx.x);
    } else {
        if (blockIdx.x >= 768) return;
        int z = blockIdx.x >> 8;
        convert_wt_body(z == 0 ? wq : z == 1 ? wk : wv,
                        z == 0 ? tq : z == 1 ? tk : tv, blockIdx.x & 255);
    }
}

// ---------------- 128x128 projection GEMM body ---------------------------------
// XCD-aware tile map: the 8 n-blocks sharing one X m-tile all get the same
// bidx%8 -> same XCD. scl: epilogue scale ((acc+bias)*scl) -- SCL2 for Q.
// SWZ=1 pre-swizzles the stored K layout for flash3's LDS staging (rule #21:
// global_load_lds dest must stay linear, so the swizzle lives in the data):
//   VMODE=0 (K): d-block index ^= (s&7)   -> Ks ds_read conflict spread
// V (VMODE=1) is read global->VGPR in flash3, so it stays UNswizzled (SWZ=0).
template <int VMODE, int SWZ>
__device__ __forceinline__
void proj_body(const _Float16* __restrict__ X, const _Float16* __restrict__ WT,
               const float* __restrict__ bias, _Float16* __restrict__ out,
               int bidx, float scl)
{
    __shared__ __attribute__((aligned(16))) _Float16 As[128 * 64];
    __shared__ __attribute__((aligned(16))) _Float16 Bs[128 * 64];
    const int tid = threadIdx.x;
    const int wave = tid >> 6, lane = tid & 63, quad = lane >> 4, l16 = lane & 15;
    const int wm = wave >> 1, wn = wave & 1;
    const int m0 = ((bidx & 7) | ((bidx >> 6) << 3)) << 7;
    const int n0 = ((bidx >> 3) & 7) << 7;
    const int lrow = lane >> 3;
    const int lcol = (lane & 7) << 3;

    floatx4 acc[4][4] = {};

    for (int k0 = 0; k0 < DMODEL; k0 += 64) {
        __syncthreads();
        #pragma unroll
        for (int c = 0; c < 4; c++) {
            int row = c * 32 + wave * 8;
            gload_lds16(X + (size_t)(m0 + row + lrow) * DMODEL + k0 + lcol,
                        As + (size_t)row * 64);
            gload_lds16(WT + (size_t)(n0 + row + lrow) * DMODEL + k0 + lcol,
                        Bs + (size_t)row * 64);
        }
        __syncthreads();
        #pragma unroll
        for (int ks = 0; ks < 2; ks++) {
            int ccol = ((ks * 4 + quad) ^ (l16 & 7)) << 3;
            half8 af[4], bf[4];
            #pragma unroll
            for (int i = 0; i < 4; i++)
                af[i] = *(const half8*)(As + (wm * 64 + i * 16 + l16) * 64 + ccol);
            #pragma unroll
            for (int j = 0; j < 4; j++)
                bf[j] = *(const half8*)(Bs + (wn * 64 + j * 16 + l16) * 64 + ccol);
            #pragma unroll
            for (int i = 0; i < 4; i++)
                #pragma unroll
                for (int j = 0; j < 4; j++)
                    acc[i][j] = VMODE ? MFMA16(bf[j], af[i], acc[i][j])
                                      : MFMA16(af[i], bf[j], acc[i][j]);
        }
    }

    if (VMODE == 0) {
        #pragma unroll
        for (int j = 0; j < 4; j++) {
            int ng = n0 + wn * 64 + j * 16 + l16;
            int h = ng >> 6, d = ng & 63;
            float bv = bias[ng];
            #pragma unroll
            for (int i = 0; i < 4; i++)
                #pragma unroll
                for (int r = 0; r < 4; r++) {
                    int mg = m0 + wm * 64 + i * 16 + quad * 4 + r;
                    int bb = mg >> 11, s = mg & 2047;
                    int dd = SWZ ? ((((d >> 3) ^ (s & 7)) << 3) | (d & 7)) : d;
                    out[(((size_t)bb * HH + h) * SS + s) * DKK + dd] =
                        (_Float16)((acc[i][j][r] + bv) * scl);
                }
        }
    } else {
        #pragma unroll
        for (int j = 0; j < 4; j++)
            #pragma unroll
            for (int r = 0; r < 4; r++) {
                int ng = n0 + wn * 64 + j * 16 + quad * 4 + r;
                int h = ng >> 6, d = ng & 63;
                float bv = bias[ng];
                #pragma unroll
                for (int i = 0; i < 4; i++) {
                    int mg = m0 + wm * 64 + i * 16 + l16;
                    int bb = mg >> 11, s = mg & 2047;
                    int ss2 = SWZ ? (s ^ ((d & 7) << 3)) : s;
                    out[(((size_t)bb * HH + h) * DKK + d) * SS + ss2] =
                        (_Float16)((acc[i][j][r] + bv) * scl);
                }
            }
    }
}

template <int VMODE, int SWZ>
__global__ __launch_bounds__(256)
void proj128(const _Float16* __restrict__ X, const _Float16* __restrict__ WT,
             const float* __restrict__ bias, _Float16* __restrict__ out, float scl)
{
    proj_body<VMODE, SWZ>(X, WT, bias, out, blockIdx.x, scl);
}

// all three projections in one launch (requires non-aliased buffers)
__global__ __launch_bounds__(256)
void proj_all(const _Float16* __restrict__ Xq, const _Float16* __restrict__ Xk,
              const _Float16* __restrict__ Xv, const _Float16* __restrict__ WTq,
              const _Float16* __restrict__ WTk, const _Float16* __restrict__ WTv,
              const float* __restrict__ bq, const float* __restrict__ bk,
              const float* __restrict__ bv, _Float16* __restrict__ Qh,
              _Float16* __restrict__ Kh, _Float16* __restrict__ VTh)
{
    int z = blockIdx.y;
    if (z == 0)      proj_body<0, 0>(Xq, WTq, bq, Qh, blockIdx.x, SCL2);
    else if (z == 1) proj_body<0, 1>(Xk, WTk, bk, Kh, blockIdx.x, 1.0f);
    else             proj_body<1, 0>(Xv, WTv, bv, VTh, blockIdx.x, 1.0f);
}

// ---------------- flash attention v6: 28KB LDS -> 2 blocks/CU ------------------
// K staged via async DMA (double-buffered, counted vmcnt(2), raw s_barrier);
// V read global->VGPR issued after QK^T (softmax hides the L2 latency);
// Bias in fp16 (-30000 sentinel); Plds collapsed to [4][16][64] (per-mt reuse
// is safe: same-wave DS ops execute in order). Total LDS 4+8+16 = 28KB so two
// blocks co-reside in the effective 64KB/CU pool (R0/R2 occupancy evidence).
__global__ __launch_bounds__(256)
void flash3(const _Float16* __restrict__ Qw, const _Float16* __restrict__ Kw,
            const _Float16* __restrict__ VTw, const int* __restrict__ mask,
            const float* __restrict__ resid, float* __restrict__ out)
{
    __shared__ _Float16 BiasH[SS];                                        // 4 KB
    __shared__ __attribute__((aligned(16))) _Float16 Plds[4][16][64];     // 8 KB
    __shared__ __attribute__((aligned(16))) _Float16 Ks[2][4096];         // 16 KB

    const int tid = threadIdx.x;
    const int wave = tid >> 6, lane = tid & 63, quad = lane >> 4, l16 = lane & 15;
    const int bx = blockIdx.x;
    const int xcd = bx & 7;
    const int jj = bx >> 3;
    const int bh = ((jj >> 4) << 3) | xcd;   // all 16 q-tiles of a bh on one XCD
    const int qt = jj & 15;
    const int b = bh >> 4;
    const int h = bh & 15;
    const int qbase = qt * 128 + wave * 32;
    const int sw = l16 & 7;

    const _Float16* Kbase = Kw + (size_t)bh * SS * DKK;
    const _Float16* Vbase = VTw + (size_t)bh * DKK * SS;

    // Q B-frags (drain under the first counted vmcnt)
    half8 qf[2][2];
    #pragma unroll
    for (int mt = 0; mt < 2; mt++) {
        const _Float16* Qp = Qw + ((size_t)bh * SS + qbase + mt * 16 + l16) * DKK;
        qf[mt][0] = *(const half8*)(Qp + quad * 8);
        qf[mt][1] = *(const half8*)(Qp + 32 + quad * 8);
    }

    // prologue: stage K tile kt=0 (2 async DMA loads per thread)
    #pragma unroll
    for (int c = 0; c < 2; c++) {
        int chunk = wave * 2 + c;
        gload_lds16(Kbase + chunk * 512 + lane * 8, &Ks[0][chunk * 512]);
    }

    // stage mask -> fp16 additive bias (exp2 domain; -30000 kills)
    const int* mk = mask + b * SS;
    for (int i = tid; i < SS; i += 256)
        BiasH[i] = mk[i] ? (_Float16)0.0f : (_Float16)-30000.0f;
    // Bias visibility barrier WITHOUT draining vmcnt (keep DMA in flight)
    asm volatile("s_waitcnt lgkmcnt(0)" ::: "memory");
    __builtin_amdgcn_s_barrier();

    float mrow[2] = {-3.0e38f, -3.0e38f};
    float lrow[2] = {0.f, 0.f};
    floatx4 oacc[2][4] = {};   // O^T: [mt][dt]; col=l16=q, row=quad*4+r=d-local

    for (int kt = 0; kt < SS / 64; kt++) {
        const int cur = kt & 1;
        const _Float16* Kl = Ks[cur];
        const int kb = kt << 6;

        // prefetch next K tile, then force current tile landed (counted wait:
        // DMA(kt) is a whole iteration old, so this is ~free)
        if (kt < SS / 64 - 1) {
            const int kb1 = kb + 64;
            #pragma unroll
            for (int c = 0; c < 2; c++) {
                int chunk = wave * 2 + c;
                gload_lds16(Kbase + (size_t)kb1 * DKK + chunk * 512 + lane * 8,
                            &Ks[cur ^ 1][chunk * 512]);
            }
            asm volatile("s_waitcnt vmcnt(2)" ::: "memory");
        } else {
            asm volatile("s_waitcnt vmcnt(0)" ::: "memory");
        }
        __builtin_amdgcn_s_barrier();   // B1: Ks[cur] visible to all waves

        // acc init = mask bias (fp16 -> f32), keys kb + k2*16 + quad*4 + r
        floatx4 sacc[2][4];
        #pragma unroll
        for (int k2 = 0; k2 < 4; k2++) {
            half4 bh4 = *(const half4*)&BiasH[kb + k2 * 16 + quad * 4];
            floatx4 bi = {(float)bh4[0], (float)bh4[1], (float)bh4[2], (float)bh4[3]};
            sacc[0][k2] = bi;
            sacc[1][k2] = bi;
        }

        // QK^T with reduced kf live-range: one ks-slice of K at a time
        __builtin_amdgcn_s_setprio(1);
        #pragma unroll
        for (int ks = 0; ks < 2; ks++) {
            half8 kf[4];
            #pragma unroll
            for (int k2 = 0; k2 < 4; k2++)
                kf[k2] = *(const half8*)(Kl + (k2 * 16 + l16) * 64
                                + (((ks * 4 + quad) ^ sw) << 3));
            #pragma unroll
            for (int mt = 0; mt < 2; mt++)
                #pragma unroll
                for (int k2 = 0; k2 < 4; k2++)
                    sacc[mt][k2] = MFMA16(kf[k2], qf[mt][ks], sacc[mt][k2]);
        }
        __builtin_amdgcn_s_setprio(0);

        // V^T A-frags: direct global loads (unswizzled layout), issued here so
        // the softmax below hides their latency
        half8 vf[2][4];
        #pragma unroll
        for (int ks = 0; ks < 2; ks++)
            #pragma unroll
            for (int dt = 0; dt < 4; dt++)
                vf[ks][dt] = *(const half8*)(Vbase
                    + (size_t)(dt * 16 + l16) * SS + kb + ks * 32 + quad * 8);

        #pragma unroll
        for (int mt = 0; mt < 2; mt++) {
            floatx4* S = sacc[mt];

            // row max: depth-4 tree + cross-quad (lanes ^16, ^32)
            float t4[4];
            #pragma unroll
            for (int k2 = 0; k2 < 4; k2++)
                t4[k2] = fmaxf(fmaxf(S[k2][0], S[k2][1]),
                               fmaxf(S[k2][2], S[k2][3]));
            float t = fmaxf(fmaxf(t4[0], t4[1]), fmaxf(t4[2], t4[3]));
            t = fmaxf(t, __shfl_xor(t, 16, 64));
            t = fmaxf(t, __shfl_xor(t, 32, 64));

            float mn = fmaxf(mrow[mt], t);
            float al = exp2f(mrow[mt] - mn);
            mrow[mt] = mn;

            // exp2 in place, write P to LDS ASAP, partial-sum tree
            float ss[4];
            #pragma unroll
            for (int k2 = 0; k2 < 4; k2++) {
                #pragma unroll
                for (int r = 0; r < 4; r++)
                    S[k2][r] = exp2f(S[k2][r] - mn);
                union { fp16x2 h2[2]; half4 h4; } u;
                u.h2[0] = __builtin_amdgcn_cvt_pkrtz(S[k2][0], S[k2][1]);
                u.h2[1] = __builtin_amdgcn_cvt_pkrtz(S[k2][2], S[k2][3]);
                int cbw = ((((k2 << 1) | (quad >> 1)) ^ sw) << 3) | ((quad & 1) << 2);
                *(half4*)&Plds[wave][l16][cbw] = u.h4;
                ss[k2] = (S[k2][0] + S[k2][1]) + (S[k2][2] + S[k2][3]);
            }
            float ps = (ss[0] + ss[1]) + (ss[2] + ss[3]);
            ps += __shfl_xor(ps, 16, 64);
            ps += __shfl_xor(ps, 32, 64);
            lrow[mt] = lrow[mt] * al + ps;

            // alpha rescale
            #pragma unroll
            for (int dt = 0; dt < 4; dt++)
                oacc[mt][dt] *= al;

            // PV: O^T += V^T x P^T  (A=vf m=d, B=pf n=q); swizzled b128 reads
            __builtin_amdgcn_s_setprio(1);
            #pragma unroll
            for (int ks = 0; ks < 2; ks++) {
                half8 pf = *(const half8*)
                    &Plds[wave][l16][((ks * 4 + quad) ^ sw) << 3];
                #pragma unroll
                for (int dt = 0; dt < 4; dt++)
                    oacc[mt][dt] = MFMA16(vf[ks][dt], pf, oacc[mt][dt]);
            }
            __builtin_amdgcn_s_setprio(0);
        }
        __builtin_amdgcn_s_barrier();   // B2: all done reading Ks[cur]
    }

    // epilogue: float4 loads/stores
    #pragma unroll
    for (int mt = 0; mt < 2; mt++) {
        float rl = 1.0f / lrow[mt];
        int s = qbase + mt * 16 + l16;
        size_t rowoff = ((size_t)b * SS + s) * DMODEL + h * DKK;
        #pragma unroll
        for (int dt = 0; dt < 4; dt++) {
            size_t gi = rowoff + dt * 16 + quad * 4;
            float4 rv = *(const float4*)&resid[gi];
            float4 ov;
            ov.x = oacc[mt][dt][0] * rl + rv.x;
            ov.y = oacc[mt][dt][1] * rl + rv.y;
            ov.z = oacc[mt][dt][2] * rl + rv.z;
            ov.w = oacc[mt][dt][3] * rl + rv.w;
            *(float4*)&out[gi] = ov;
        }
    }
}

// ---------------------------------------------------------------------------
extern "C" void kernel_launch(void* const* d_in, const int* in_sizes, int n_in,
                              void* d_out, int out_size, void* d_ws, size_t ws_size,
                              hipStream_t stream)
{
    const float* q    = (const float*)d_in[0];
    const float* k    = (const float*)d_in[1];
    const float* v    = (const float*)d_in[2];
    const int*   mask = (const int*)d_in[3];
    const float* wq   = (const float*)d_in[4];
    const float* bq   = (const float*)d_in[5];
    const float* wk   = (const float*)d_in[6];
    const float* bk   = (const float*)d_in[7];
    const float* wv   = (const float*)d_in[8];
    const float* bv   = (const float*)d_in[9];
    float* out = (float*)d_out;

    const size_t TENS = (size_t)BB * SS * HH * DKK;   // 8388608 halves
    const size_t WSZ  = (size_t)DMODEL * DMODEL;      // 1048576 halves
    _Float16* base = (_Float16*)d_ws;

    bool big = ws_size >= (6 * TENS + 3 * WSZ) * sizeof(_Float16);
    _Float16 *Xq, *Xk, *Xv, *Qh, *Kh, *VTh, *WTq;
    if (big) {
        Xq = base;            Xk = base + TENS;     Xv = base + 2 * TENS;
        Qh = base + 3 * TENS; Kh = base + 4 * TENS; VTh = base + 5 * TENS;
        WTq = base + 6 * TENS;
    } else {
        // stream-ordered aliasing: Kh reuses Xq's slot, VTh reuses Xk's slot
        Xq = base;            Xk = base + TENS;     Xv = base + 2 * TENS;
        Qh = base + 3 * TENS; Kh = Xq;              VTh = Xk;
        WTq = base + 4 * TENS;
    }
    _Float16* WTk = WTq + WSZ;
    _Float16* WTv = WTk + WSZ;

    if (big) {
        hipLaunchKernelGGL(convert_all, dim3(4096, 4), dim3(256), 0, stream,
                           q, k, v, wq, wk, wv, Xq, Xk, Xv, WTq, WTk, WTv);
        hipLaunchKernelGGL(proj_all, dim3(512, 3), dim3(256), 0, stream,
                           Xq, Xk, Xv, WTq, WTk, WTv, bq, bk, bv, Qh, Kh, VTh);
    } else {
        hipLaunchKernelGGL(convert_x, dim3(4096, 3), dim3(256), 0, stream,
                           q, k, v, Xq, Xk, Xv);
        hipLaunchKernelGGL(convert_wt, dim3(256, 3), dim3(256), 0, stream,
                           wq, wk, wv, WTq, WTk, WTv);
        hipLaunchKernelGGL((proj128<0, 0>), dim3(512), dim3(256), 0, stream, Xq, WTq, bq, Qh, SCL2);
        hipLaunchKernelGGL((proj128<0, 1>), dim3(512), dim3(256), 0, stream, Xk, WTk, bk, Kh, 1.0f);
        hipLaunchKernelGGL((proj128<1, 0>), dim3(512), dim3(256), 0, stream, Xv, WTv, bv, VTh, 1.0f);
    }
    hipLaunchKernelGGL(flash3, dim3(BB * HH * (SS / 128)), dim3(256), 0, stream,
                       Qh, Kh, VTh, mask, q, out);
}

// Round 5
// 461.050 us; speedup vs baseline: 1.1187x; 1.0177x over previous
//
#include <hip/hip_runtime.h>
#include <hip/hip_fp16.h>

#define BB 4
#define SS 2048
#define HH 16
#define DKK 64
#define DMODEL 1024

typedef __attribute__((ext_vector_type(8))) _Float16 half8;
typedef __attribute__((ext_vector_type(4))) _Float16 half4;
typedef __attribute__((ext_vector_type(2))) __fp16 fp16x2;
typedef __attribute__((ext_vector_type(4))) float floatx4;

#define MFMA16(a, b, c) __builtin_amdgcn_mfma_f32_16x16x32_f16(a, b, c, 0, 0, 0)

// 8 * log2(e): reference scale is *8; softmax runs in exp2 domain.
// Folded into the Q projection epilogue (Qh is pre-scaled).
#define SCL2 11.5415603336f

// ---------------- async global->LDS, 16B per lane ------------------------------
__device__ __forceinline__ void gload_lds16(const _Float16* g, _Float16* l) {
    __builtin_amdgcn_global_load_lds(
        (const __attribute__((address_space(1))) void*)g,
        (__attribute__((address_space(3))) void*)l, 16, 0, 0);
}

// ---------------- cross-quad butterflies (proven __shfl_xor form) --------------
// R4's permlane-swap inline asm broke the max reduction on HW (absmax ~ 2^110
// = exp2 overflow from a missed row max). Reverted to the R0-R3-proven shfl;
// a builtin-based permlane retry is a future isolated experiment.
__device__ __forceinline__ float qred_max(float t) {
    t = fmaxf(t, __shfl_xor(t, 16, 64));
    t = fmaxf(t, __shfl_xor(t, 32, 64));
    return t;
}
__device__ __forceinline__ float qred_sum(float t) {
    t += __shfl_xor(t, 16, 64);
    t += __shfl_xor(t, 32, 64);
    return t;
}

// ---------------- fp32 -> fp16 convert of X body, k-unit XOR swizzle -----------
__device__ __forceinline__
void convert_x_body(const float* __restrict__ src, _Float16* __restrict__ dst,
                    int bidx)
{
    size_t base = ((size_t)bidx * 256 + threadIdx.x) * 8;
    int m = (int)(base >> 10);
    int kk = (int)(base & 1023);
    float4 a = *(const float4*)(src + base);
    float4 b = *(const float4*)(src + base + 4);
    half8 h;
    h[0] = (_Float16)a.x; h[1] = (_Float16)a.y; h[2] = (_Float16)a.z; h[3] = (_Float16)a.w;
    h[4] = (_Float16)b.x; h[5] = (_Float16)b.y; h[6] = (_Float16)b.z; h[7] = (_Float16)b.w;
    int kd = kk ^ ((m & 7) << 3);
    *(half8*)(dst + ((size_t)m << 10) + kd) = h;
}

// ---------------- W[k][n] -> WT[n][k] fp16 body, swizzle by (n&7) --------------
__device__ __forceinline__
void convert_wt_body(const float* __restrict__ W, _Float16* __restrict__ WT,
                     int bidx)
{
    __shared__ __attribute__((aligned(16))) _Float16 T[64][72];
    int kt = (bidx >> 4) << 6;
    int nt = (bidx & 15) << 6;
    int tid = threadIdx.x;
    #pragma unroll
    for (int p = 0; p < 4; p++) {
        int lin = tid + p * 256;
        int row = lin >> 4;
        int c4 = (lin & 15) << 2;
        float4 vv = *(const float4*)(W + (size_t)(kt + row) * DMODEL + nt + c4);
        T[c4 + 0][row] = (_Float16)vv.x;
        T[c4 + 1][row] = (_Float16)vv.y;
        T[c4 + 2][row] = (_Float16)vv.z;
        T[c4 + 3][row] = (_Float16)vv.w;
    }
    __syncthreads();
    #pragma unroll
    for (int p = 0; p < 2; p++) {
        int lin = tid + p * 256;
        int nl = lin >> 3;
        int u = lin & 7;
        half8 h = *(const half8*)&T[nl][u * 8];
        int n = nt + nl;
        int kd = kt + ((u ^ (n & 7)) << 3);
        *(half8*)(WT + (size_t)n * DMODEL + kd) = h;
    }
}

__global__ __launch_bounds__(256)
void convert_x(const float* __restrict__ q, const float* __restrict__ k,
               const float* __restrict__ v, _Float16* __restrict__ xq,
               _Float16* __restrict__ xk, _Float16* __restrict__ xv)
{
    int z = blockIdx.y;
    convert_x_body(z == 0 ? q : z == 1 ? k : v,
                   z == 0 ? xq : z == 1 ? xk : xv, blockIdx.x);
}

__global__ __launch_bounds__(256)
void convert_wt(const float* __restrict__ wq, const float* __restrict__ wk,
                const float* __restrict__ wv, _Float16* __restrict__ tq,
                _Float16* __restrict__ tk, _Float16* __restrict__ tv)
{
    int z = blockIdx.y;
    convert_wt_body(z == 0 ? wq : z == 1 ? wk : wv,
                    z == 0 ? tq : z == 1 ? tk : tv, blockIdx.x);
}

// fused converts: y=0..2 -> X converts; y=3 -> the 768 WT blocks
__global__ __launch_bounds__(256)
void convert_all(const float* __restrict__ q, const float* __restrict__ k,
                 const float* __restrict__ v, const float* __restrict__ wq,
                 const float* __restrict__ wk, const float* __restrict__ wv,
                 _Float16* __restrict__ xq, _Float16* __restrict__ xk,
                 _Float16* __restrict__ xv, _Float16* __restrict__ tq,
                 _Float16* __restrict__ tk, _Float16* __restrict__ tv)
{
    int y = blockIdx.y;
    if (y < 3) {
        convert_x_body(y == 0 ? q : y == 1 ? k : v,
                       y == 0 ? xq : y == 1 ? xk : xv, blockIdx.x);
    } else {
        if (blockIdx.x >= 768) return;
        int z = blockIdx.x >> 8;
        convert_wt_body(z == 0 ? wq : z == 1 ? wk : wv,
                        z == 0 ? tq : z == 1 ? tk : tv, blockIdx.x & 255);
    }
}

// ---------------- 128x128 projection GEMM body ---------------------------------
// XCD-aware tile map: the 8 n-blocks sharing one X m-tile all get the same
// bidx%8 -> same XCD. scl: epilogue scale ((acc+bias)*scl) -- SCL2 for Q.
// SWZ=1 pre-swizzles the stored K layout for flash3's LDS staging (rule #21:
// global_load_lds dest must stay linear, so the swizzle lives in the data):
//   VMODE=0 (K): d-block index ^= (s&7)   -> Ks ds_read conflict spread
// V (VMODE=1) is read global->VGPR in flash3, so it stays UNswizzled (SWZ=0).
template <int VMODE, int SWZ>
__device__ __forceinline__
void proj_body(const _Float16* __restrict__ X, const _Float16* __restrict__ WT,
               const float* __restrict__ bias, _Float16* __restrict__ out,
               int bidx, float scl)
{
    __shared__ __attribute__((aligned(16))) _Float16 As[128 * 64];
    __shared__ __attribute__((aligned(16))) _Float16 Bs[128 * 64];
    const int tid = threadIdx.x;
    const int wave = tid >> 6, lane = tid & 63, quad = lane >> 4, l16 = lane & 15;
    const int wm = wave >> 1, wn = wave & 1;
    const int m0 = ((bidx & 7) | ((bidx >> 6) << 3)) << 7;
    const int n0 = ((bidx >> 3) & 7) << 7;
    const int lrow = lane >> 3;
    const int lcol = (lane & 7) << 3;

    floatx4 acc[4][4] = {};

    for (int k0 = 0; k0 < DMODEL; k0 += 64) {
        __syncthreads();
        #pragma unroll
        for (int c = 0; c < 4; c++) {
            int row = c * 32 + wave * 8;
            gload_lds16(X + (size_t)(m0 + row + lrow) * DMODEL + k0 + lcol,
                        As + (size_t)row * 64);
            gload_lds16(WT + (size_t)(n0 + row + lrow) * DMODEL + k0 + lcol,
                        Bs + (size_t)row * 64);
        }
        __syncthreads();
        #pragma unroll
        for (int ks = 0; ks < 2; ks++) {
            int ccol = ((ks * 4 + quad) ^ (l16 & 7)) << 3;
            half8 af[4], bf[4];
            #pragma unroll
            for (int i = 0; i < 4; i++)
                af[i] = *(const half8*)(As + (wm * 64 + i * 16 + l16) * 64 + ccol);
            #pragma unroll
            for (int j = 0; j < 4; j++)
                bf[j] = *(const half8*)(Bs + (wn * 64 + j * 16 + l16) * 64 + ccol);
            #pragma unroll
            for (int i = 0; i < 4; i++)
                #pragma unroll
                for (int j = 0; j < 4; j++)
                    acc[i][j] = VMODE ? MFMA16(bf[j], af[i], acc[i][j])
                                      : MFMA16(af[i], bf[j], acc[i][j]);
        }
    }

    if (VMODE == 0) {
        #pragma unroll
        for (int j = 0; j < 4; j++) {
            int ng = n0 + wn * 64 + j * 16 + l16;
            int h = ng >> 6, d = ng & 63;
            float bv = bias[ng];
            #pragma unroll
            for (int i = 0; i < 4; i++)
                #pragma unroll
                for (int r = 0; r < 4; r++) {
                    int mg = m0 + wm * 64 + i * 16 + quad * 4 + r;
                    int bb = mg >> 11, s = mg & 2047;
                    int dd = SWZ ? ((((d >> 3) ^ (s & 7)) << 3) | (d & 7)) : d;
                    out[(((size_t)bb * HH + h) * SS + s) * DKK + dd] =
                        (_Float16)((acc[i][j][r] + bv) * scl);
                }
        }
    } else {
        #pragma unroll
        for (int j = 0; j < 4; j++)
            #pragma unroll
            for (int r = 0; r < 4; r++) {
                int ng = n0 + wn * 64 + j * 16 + quad * 4 + r;
                int h = ng >> 6, d = ng & 63;
                float bv = bias[ng];
                #pragma unroll
                for (int i = 0; i < 4; i++) {
                    int mg = m0 + wm * 64 + i * 16 + l16;
                    int bb = mg >> 11, s = mg & 2047;
                    int ss2 = SWZ ? (s ^ ((d & 7) << 3)) : s;
                    out[(((size_t)bb * HH + h) * DKK + d) * SS + ss2] =
                        (_Float16)((acc[i][j][r] + bv) * scl);
                }
            }
    }
}

template <int VMODE, int SWZ>
__global__ __launch_bounds__(256)
void proj128(const _Float16* __restrict__ X, const _Float16* __restrict__ WT,
             const float* __restrict__ bias, _Float16* __restrict__ out, float scl)
{
    proj_body<VMODE, SWZ>(X, WT, bias, out, blockIdx.x, scl);
}

// all three projections in one launch (requires non-aliased buffers)
__global__ __launch_bounds__(256)
void proj_all(const _Float16* __restrict__ Xq, const _Float16* __restrict__ Xk,
              const _Float16* __restrict__ Xv, const _Float16* __restrict__ WTq,
              const _Float16* __restrict__ WTk, const _Float16* __restrict__ WTv,
              const float* __restrict__ bq, const float* __restrict__ bk,
              const float* __restrict__ bv, _Float16* __restrict__ Qh,
              _Float16* __restrict__ Kh, _Float16* __restrict__ VTh)
{
    int z = blockIdx.y;
    if (z == 0)      proj_body<0, 0>(Xq, WTq, bq, Qh, blockIdx.x, SCL2);
    else if (z == 1) proj_body<0, 1>(Xk, WTk, bk, Kh, blockIdx.x, 1.0f);
    else             proj_body<1, 0>(Xv, WTv, bv, VTh, blockIdx.x, 1.0f);
}

// ---------------- flash attention v8: vmcnt-queue fix, shfl reductions ---------
// K staged via async DMA (double-buffered). vf (V) global loads are issued at
// loop TOP, BEFORE the K-prefetch DMA, so each iteration contributes exactly
// 10 VMEM ops (8 vf + 2 K-DMA): the counted vmcnt(10) provably drains all
// prior-iteration ops (incl. the current tile's K DMA) while keeping this
// iteration's vf + next-tile prefetch in flight (T4). The compiler's own wait
// at PV then only needs vmcnt(2) -- the K prefetch is never force-drained.
__global__ __launch_bounds__(256)
void flash3(const _Float16* __restrict__ Qw, const _Float16* __restrict__ Kw,
            const _Float16* __restrict__ VTw, const int* __restrict__ mask,
            const float* __restrict__ resid, float* __restrict__ out)
{
    __shared__ _Float16 BiasH[SS];                                        // 4 KB
    __shared__ __attribute__((aligned(16))) _Float16 Plds[4][16][64];     // 8 KB
    __shared__ __attribute__((aligned(16))) _Float16 Ks[2][4096];         // 16 KB

    const int tid = threadIdx.x;
    const int wave = tid >> 6, lane = tid & 63, quad = lane >> 4, l16 = lane & 15;
    const int bx = blockIdx.x;
    const int xcd = bx & 7;
    const int jj = bx >> 3;
    const int bh = ((jj >> 4) << 3) | xcd;   // all 16 q-tiles of a bh on one XCD
    const int qt = jj & 15;
    const int b = bh >> 4;
    const int h = bh & 15;
    const int qbase = qt * 128 + wave * 32;
    const int sw = l16 & 7;

    const _Float16* Kbase = Kw + (size_t)bh * SS * DKK;
    const _Float16* Vbase = VTw + (size_t)bh * DKK * SS;

    // Q B-frags (oldest in the VMEM queue; drained by the first counted wait)
    half8 qf[2][2];
    #pragma unroll
    for (int mt = 0; mt < 2; mt++) {
        const _Float16* Qp = Qw + ((size_t)bh * SS + qbase + mt * 16 + l16) * DKK;
        qf[mt][0] = *(const half8*)(Qp + quad * 8);
        qf[mt][1] = *(const half8*)(Qp + 32 + quad * 8);
    }

    // prologue: stage K tile kt=0 (2 async DMA loads per thread)
    #pragma unroll
    for (int c = 0; c < 2; c++) {
        int chunk = wave * 2 + c;
        gload_lds16(Kbase + chunk * 512 + lane * 8, &Ks[0][chunk * 512]);
    }

    // stage mask -> fp16 additive bias (exp2 domain; -30000 kills)
    const int* mk = mask + b * SS;
    for (int i = tid; i < SS; i += 256)
        BiasH[i] = mk[i] ? (_Float16)0.0f : (_Float16)-30000.0f;
    // Bias visibility barrier WITHOUT draining vmcnt (keep DMA in flight)
    asm volatile("s_waitcnt lgkmcnt(0)" ::: "memory");
    __builtin_amdgcn_s_barrier();

    float mrow[2] = {-3.0e38f, -3.0e38f};
    float lrow[2] = {0.f, 0.f};
    floatx4 oacc[2][4] = {};   // O^T: [mt][dt]; col=l16=q, row=quad*4+r=d-local

    for (int kt = 0; kt < SS / 64; kt++) {
        const int cur = kt & 1;
        const _Float16* Kl = Ks[cur];
        const int kb = kt << 6;

        // V^T A-frags for THIS tile, issued FIRST (older than the K prefetch)
        half8 vf[2][4];
        #pragma unroll
        for (int ks = 0; ks < 2; ks++)
            #pragma unroll
            for (int dt = 0; dt < 4; dt++)
                vf[ks][dt] = *(const half8*)(Vbase
                    + (size_t)(dt * 16 + l16) * SS + kb + ks * 32 + quad * 8);

        // prefetch next K tile; counted wait drains ONLY ops older than this
        // iteration's 10 (8 vf + 2 dma) => current tile's K DMA has landed.
        if (kt < SS / 64 - 1) {
            const int kb1 = kb + 64;
            #pragma unroll
            for (int c = 0; c < 2; c++) {
                int chunk = wave * 2 + c;
                gload_lds16(Kbase + (size_t)kb1 * DKK + chunk * 512 + lane * 8,
                            &Ks[cur ^ 1][chunk * 512]);
            }
            asm volatile("s_waitcnt vmcnt(10)" ::: "memory");
        } else {
            asm volatile("s_waitcnt vmcnt(8)" ::: "memory");
        }
        __builtin_amdgcn_s_barrier();   // B1: Ks[cur] visible to all waves

        // acc init = mask bias (fp16 -> f32), keys kb + k2*16 + quad*4 + r
        floatx4 sacc[2][4];
        #pragma unroll
        for (int k2 = 0; k2 < 4; k2++) {
            half4 bh4 = *(const half4*)&BiasH[kb + k2 * 16 + quad * 4];
            floatx4 bi = {(float)bh4[0], (float)bh4[1], (float)bh4[2], (float)bh4[3]};
            sacc[0][k2] = bi;
            sacc[1][k2] = bi;
        }

        // QK^T with reduced kf live-range: one ks-slice of K at a time
        __builtin_amdgcn_s_setprio(1);
        #pragma unroll
        for (int ks = 0; ks < 2; ks++) {
            half8 kf[4];
            #pragma unroll
            for (int k2 = 0; k2 < 4; k2++)
                kf[k2] = *(const half8*)(Kl + (k2 * 16 + l16) * 64
                                + (((ks * 4 + quad) ^ sw) << 3));
            #pragma unroll
            for (int mt = 0; mt < 2; mt++)
                #pragma unroll
                for (int k2 = 0; k2 < 4; k2++)
                    sacc[mt][k2] = MFMA16(kf[k2], qf[mt][ks], sacc[mt][k2]);
        }
        __builtin_amdgcn_s_setprio(0);

        #pragma unroll
        for (int mt = 0; mt < 2; mt++) {
            floatx4* S = sacc[mt];

            // row max: depth-4 in-lane tree + cross-quad shfl butterflies
            float t4[4];
            #pragma unroll
            for (int k2 = 0; k2 < 4; k2++)
                t4[k2] = fmaxf(fmaxf(S[k2][0], S[k2][1]),
                               fmaxf(S[k2][2], S[k2][3]));
            float t = fmaxf(fmaxf(t4[0], t4[1]), fmaxf(t4[2], t4[3]));
            t = qred_max(t);

            float mn = fmaxf(mrow[mt], t);
            float al = exp2f(mrow[mt] - mn);
            mrow[mt] = mn;

            // exp2 in place, write P to LDS ASAP, partial-sum tree
            float ss[4];
            #pragma unroll
            for (int k2 = 0; k2 < 4; k2++) {
                #pragma unroll
                for (int r = 0; r < 4; r++)
                    S[k2][r] = exp2f(S[k2][r] - mn);
                union { fp16x2 h2[2]; half4 h4; } u;
                u.h2[0] = __builtin_amdgcn_cvt_pkrtz(S[k2][0], S[k2][1]);
                u.h2[1] = __builtin_amdgcn_cvt_pkrtz(S[k2][2], S[k2][3]);
                int cbw = ((((k2 << 1) | (quad >> 1)) ^ sw) << 3) | ((quad & 1) << 2);
                *(half4*)&Plds[wave][l16][cbw] = u.h4;
                ss[k2] = (S[k2][0] + S[k2][1]) + (S[k2][2] + S[k2][3]);
            }
            float ps = (ss[0] + ss[1]) + (ss[2] + ss[3]);
            ps = qred_sum(ps);
            lrow[mt] = lrow[mt] * al + ps;

            // alpha rescale
            #pragma unroll
            for (int dt = 0; dt < 4; dt++)
                oacc[mt][dt] *= al;

            // PV: O^T += V^T x P^T  (A=vf m=d, B=pf n=q); swizzled b128 reads
            __builtin_amdgcn_s_setprio(1);
            #pragma unroll
            for (int ks = 0; ks < 2; ks++) {
                half8 pf = *(const half8*)
                    &Plds[wave][l16][((ks * 4 + quad) ^ sw) << 3];
                #pragma unroll
                for (int dt = 0; dt < 4; dt++)
                    oacc[mt][dt] = MFMA16(vf[ks][dt], pf, oacc[mt][dt]);
            }
            __builtin_amdgcn_s_setprio(0);
        }
        __builtin_amdgcn_s_barrier();   // B2: all done reading Ks[cur]
    }

    // epilogue: float4 loads/stores
    #pragma unroll
    for (int mt = 0; mt < 2; mt++) {
        float rl = 1.0f / lrow[mt];
        int s = qbase + mt * 16 + l16;
        size_t rowoff = ((size_t)b * SS + s) * DMODEL + h * DKK;
        #pragma unroll
        for (int dt = 0; dt < 4; dt++) {
            size_t gi = rowoff + dt * 16 + quad * 4;
            float4 rv = *(const float4*)&resid[gi];
            float4 ov;
            ov.x = oacc[mt][dt][0] * rl + rv.x;
            ov.y = oacc[mt][dt][1] * rl + rv.y;
            ov.z = oacc[mt][dt][2] * rl + rv.z;
            ov.w = oacc[mt][dt][3] * rl + rv.w;
            *(float4*)&out[gi] = ov;
        }
    }
}

// ---------------------------------------------------------------------------
extern "C" void kernel_launch(void* const* d_in, const int* in_sizes, int n_in,
                              void* d_out, int out_size, void* d_ws, size_t ws_size,
                              hipStream_t stream)
{
    const float* q    = (const float*)d_in[0];
    const float* k    = (const float*)d_in[1];
    const float* v    = (const float*)d_in[2];
    const int*   mask = (const int*)d_in[3];
    const float* wq   = (const float*)d_in[4];
    const float* bq   = (const float*)d_in[5];
    const float* wk   = (const float*)d_in[6];
    const float* bk   = (const float*)d_in[7];
    const float* wv   = (const float*)d_in[8];
    const float* bv   = (const float*)d_in[9];
    float* out = (float*)d_out;

    const size_t TENS = (size_t)BB * SS * HH * DKK;   // 8388608 halves
    const size_t WSZ  = (size_t)DMODEL * DMODEL;      // 1048576 halves
    _Float16* base = (_Float16*)d_ws;

    bool big = ws_size >= (6 * TENS + 3 * WSZ) * sizeof(_Float16);
    _Float16 *Xq, *Xk, *Xv, *Qh, *Kh, *VTh, *WTq;
    if (big) {
        Xq = base;            Xk = base + TENS;     Xv = base + 2 * TENS;
        Qh = base + 3 * TENS; Kh = base + 4 * TENS; VTh = base + 5 * TENS;
        WTq = base + 6 * TENS;
    } else {
        // stream-ordered aliasing: Kh reuses Xq's slot, VTh reuses Xk's slot
        Xq = base;            Xk = base + TENS;     Xv = base + 2 * TENS;
        Qh = base + 3 * TENS; Kh = Xq;              VTh = Xk;
        WTq = base + 4 * TENS;
    }
    _Float16* WTk = WTq + WSZ;
    _Float16* WTv = WTk + WSZ;

    if (big) {
        hipLaunchKernelGGL(convert_all, dim3(4096, 4), dim3(256), 0, stream,
                           q, k, v, wq, wk, wv, Xq, Xk, Xv, WTq, WTk, WTv);
        hipLaunchKernelGGL(proj_all, dim3(512, 3), dim3(256), 0, stream,
                           Xq, Xk, Xv, WTq, WTk, WTv, bq, bk, bv, Qh, Kh, VTh);
    } else {
        hipLaunchKernelGGL(convert_x, dim3(4096, 3), dim3(256), 0, stream,
                           q, k, v, Xq, Xk, Xv);
        hipLaunchKernelGGL(convert_wt, dim3(256, 3), dim3(256), 0, stream,
                           wq, wk, wv, WTq, WTk, WTv);
        hipLaunchKernelGGL((proj128<0, 0>), dim3(512), dim3(256), 0, stream, Xq, WTq, bq, Qh, SCL2);
        hipLaunchKernelGGL((proj128<0, 1>), dim3(512), dim3(256), 0, stream, Xk, WTk, bk, Kh, 1.0f);
        hipLaunchKernelGGL((proj128<1, 0>), dim3(512), dim3(256), 0, stream, Xv, WTv, bv, VTh, 1.0f);
    }
    hipLaunchKernelGGL(flash3, dim3(BB * HH * (SS / 128)), dim3(256), 0, stream,
                       Qh, Kh, VTh, mask, q, out);
}